// Round 4
// baseline (23984.621 us; speedup 1.0000x reference)
//
#include <hip/hip_runtime.h>
#include <hip/hip_bf16.h>
#include <stdint.h>

// 2-layer LSTM, B=64, T=1024, D=H=512.
// Persistent pipelined kernel: 128 WGs = 2 layers x 4 row-islands x 16 WGs.
// Each WG: 16 batch rows x 32 h-cols, 4 waves (wave = gate), W in 256 VGPRs.
// Island-local flag sync per timestep; layer 2 trails layer 1 by one step.
// bi&7 -> (layer,island): island's 16 WGs land on one XCD under %8 round-robin.

typedef short short8 __attribute__((ext_vector_type(8)));
typedef float f32x4 __attribute__((ext_vector_type(4)));

#define NT 1024
#define NB 64
#define NH 512
#define WG_PER_ISL 16
// ~5 ms at ~64cy/iter: >=50x any legitimate wait, but a deadlocked run fails
// out in seconds (caps accumulate per step), not tens of minutes.
#define SPIN_CAP 200000u

// Z_lds column swizzle: flips col bit4 keyed by row parity ^ row bit2.
// Writes (lanes differ in row bits 2-3) and reads (lanes differ in row bits 0-1)
// both become 2-way bank aliasing (free per m136) instead of 4-way.
#define ZSWZ(row, col) ((col) ^ ((((row) ^ ((row) >> 2)) & 1) << 4))

static __device__ __forceinline__ unsigned short f2bf(float f) {
    union { float f; unsigned u; } v; v.f = f;
    unsigned r = (v.u + 0x7fffu + ((v.u >> 16) & 1u)) >> 16;  // RNE
    return (unsigned short)r;
}
static __device__ __forceinline__ float sigf(float x) {
    return 1.0f / (1.0f + __expf(-x));
}
static __device__ __forceinline__ float tanh_fast(float x) {
    return 1.0f - 2.0f / (1.0f + __expf(2.0f * x));
}

// X [64][1024][512] f32 -> Xt [1024][64][512] bf16
__global__ void cvt_x_kernel(const float* __restrict__ X, unsigned short* __restrict__ Xt) {
    unsigned id = blockIdx.x * 256 + threadIdx.x;   // 4,194,304 threads, 8 elems each
    unsigned d8 = id & 63u;
    unsigned t  = (id >> 6) & 1023u;
    unsigned b  = id >> 16;
    const f32x4* src = (const f32x4*)(X + (((size_t)b * NT + t) * NH) + d8 * 8);
    f32x4 v0 = src[0], v1 = src[1];
    short8 o;
    #pragma unroll
    for (int j = 0; j < 4; ++j) o[j] = (short)f2bf(v0[j]);
    #pragma unroll
    for (int j = 0; j < 4; ++j) o[4 + j] = (short)f2bf(v1[j]);
    *(short8*)(Xt + (((size_t)t * NB + b) * NH) + d8 * 8) = o;
}

// W[l] [1024][2048] f32 -> Wp [l][wgi][g][h][c16][k1024] bf16 (B-fragment order)
__global__ void pack_w_kernel(const float* __restrict__ W1, const float* __restrict__ W2,
                              unsigned short* __restrict__ Wp) {
    unsigned id = blockIdx.x * 256 + threadIdx.x;  // 524,288 threads, 8 k each
    unsigned k8  = id & 127u;
    unsigned c   = (id >> 7) & 15u;
    unsigned h   = (id >> 11) & 1u;
    unsigned g   = (id >> 12) & 3u;
    unsigned wgi = (id >> 14) & 15u;
    unsigned l   = id >> 18;
    const float* W = l ? W2 : W1;
    unsigned n = g * 512u + wgi * 32u + h * 16u + c;
    short8 o;
    #pragma unroll
    for (int j = 0; j < 8; ++j) o[j] = (short)f2bf(W[(size_t)(k8 * 8 + j) * 2048 + n]);
    *(short8*)(Wp + (size_t)id * 8) = o;
}

__global__ __launch_bounds__(256, 1)
void lstm_kernel(const unsigned short* __restrict__ Xt,   // [1024][64][512] bf16
                 unsigned short* __restrict__ h1,         // [1024][64][512] bf16
                 unsigned short* __restrict__ hb2,        // [2][64][512] bf16 ping-pong
                 const unsigned short* __restrict__ Wp,   // packed weights bf16
                 const float* __restrict__ b1,
                 const float* __restrict__ b2,
                 float* __restrict__ out,                 // [64][1024][512] f32
                 int* __restrict__ cnt)                   // [2][4][1024]
{
    const int bi  = blockIdx.x;
    const int L   = (bi >> 2) & 1;
    const int isl = bi & 3;
    const int wgi = bi >> 3;          // 0..15
    const int tid = threadIdx.x;
    const int lane = tid & 63;
    const int w    = tid >> 6;        // wave index == gate index (i,j,f,o)

    __shared__ alignas(16) unsigned short A_lds[16 * 1024]; // [16 rows][1024 k], XOR-swizzled
    __shared__ float Z_lds[16 * 128];                       // [16 rows][4 gates * 32 hcols]

    const int lc = lane & 15;
    const int lk = lane >> 4;

    // ---- persistent weight fragments: wave w, cols n = w*512 + wgi*32 + {0..31}
    short8 wf0[32], wf1[32];
    {
        const unsigned short* wb = Wp + ((((size_t)L * 16 + wgi) * 4 + w) * 2) * (16 * 1024);
        #pragma unroll
        for (int ks = 0; ks < 32; ++ks) {
            wf0[ks] = *(const short8*)(wb + (size_t)lc * 1024 + ks * 32 + lk * 8);
            wf1[ks] = *(const short8*)(wb + (size_t)(16 + lc) * 1024 + ks * 32 + lk * 8);
        }
    }

    float c0 = 0.0f, c1 = 0.0f;       // cell state, owned per-thread
    const int er = tid >> 4;          // row 0..15
    const int ej = tid & 15;          // hcol_local (and +16)
    const int brow_e = isl * 16 + er;

    // ---- hoist loop-invariant biases into registers (FORGET_BIAS pre-folded)
    const float* bias = L ? b2 : b1;
    const int jg0 = wgi * 32 + ej, jg1 = jg0 + 16;
    const float bi_i0 = bias[jg0],          bi_i1 = bias[jg1];
    const float bi_j0 = bias[512 + jg0],    bi_j1 = bias[512 + jg1];
    const float bi_f0 = bias[1024 + jg0] + 1.0f, bi_f1 = bias[1024 + jg1] + 1.0f;
    const float bi_o0 = bias[1536 + jg0],   bi_o1 = bias[1536 + jg1];

    int* mycnt  = cnt + (L * 4 + isl) * NT;
    int* depcnt = cnt + isl * NT;     // layer-1 counters (dep for L==1)

    for (int t = 0; t < NT; ++t) {
        // ---- wait for previous step (own island) and, for layer 2, h1[t]
        if (tid == 0) {
            if (t > 0) {
                unsigned sp = 0;
                while (__hip_atomic_load(&mycnt[t - 1], __ATOMIC_RELAXED, __HIP_MEMORY_SCOPE_AGENT) < WG_PER_ISL
                       && ++sp < SPIN_CAP) __builtin_amdgcn_s_sleep(1);
            }
            if (L == 1) {
                unsigned sp = 0;
                while (__hip_atomic_load(&depcnt[t], __ATOMIC_RELAXED, __HIP_MEMORY_SCOPE_AGENT) < WG_PER_ISL
                       && ++sp < SPIN_CAP) __builtin_amdgcn_s_sleep(1);
            }
        }
        __syncthreads();
        if (t > 0) (void)__hip_atomic_load(&mycnt[t - 1], __ATOMIC_ACQUIRE, __HIP_MEMORY_SCOPE_AGENT);
        if (L == 1) (void)__hip_atomic_load(&depcnt[t], __ATOMIC_ACQUIRE, __HIP_MEMORY_SCOPE_AGENT);

        // ---- stage A = [x_t | h_{t-1}] for this island into LDS (swizzled)
        {
            const unsigned short* xsrc = (L == 0) ? (Xt + (size_t)t * (NB * NH))
                                                  : (h1 + (size_t)t * (NB * NH));
            const unsigned short* hsrc = (L == 0) ? (h1 + (size_t)(t > 0 ? t - 1 : 0) * (NB * NH))
                                                  : (hb2 + (size_t)((t + 1) & 1) * (NB * NH));
            const bool hz = (t == 0);
            #pragma unroll
            for (int p = 0; p < 8; ++p) {
                int ci = p * 256 + tid;
                int r = ci >> 7, s = ci & 127;        // per-wave uniform x/h split
                int br = isl * 16 + r;
                short8 v = {0,0,0,0,0,0,0,0};
                if (s < 64)       v = *(const short8*)(xsrc + (size_t)br * NH + s * 8);
                else if (!hz)     v = *(const short8*)(hsrc + (size_t)br * NH + (s - 64) * 8);
                *(short8*)((char*)A_lds + r * 2048 + (((s ^ (r & 7))) << 4)) = v;
            }
        }
        __syncthreads();

        // ---- Z = A @ W (K=1024), per wave: 2 col-tiles x 32 k-steps, 2 acc chains each
        {
            f32x4 a00 = {0,0,0,0}, a01 = {0,0,0,0}, a10 = {0,0,0,0}, a11 = {0,0,0,0};
            const char* ab = (const char*)A_lds + lc * 2048;
            const int sw = lc & 7;
            #pragma unroll
            for (int ks = 0; ks < 32; ++ks) {
                short8 a = *(const short8*)(ab + (((ks * 4 + lk) ^ sw) << 4));
                if (ks & 1) {
                    a01 = __builtin_amdgcn_mfma_f32_16x16x32_bf16(a, wf0[ks], a01, 0, 0, 0);
                    a11 = __builtin_amdgcn_mfma_f32_16x16x32_bf16(a, wf1[ks], a11, 0, 0, 0);
                } else {
                    a00 = __builtin_amdgcn_mfma_f32_16x16x32_bf16(a, wf0[ks], a00, 0, 0, 0);
                    a10 = __builtin_amdgcn_mfma_f32_16x16x32_bf16(a, wf1[ks], a10, 0, 0, 0);
                }
            }
            f32x4 z0 = a00 + a01, z1 = a10 + a11;
            #pragma unroll
            for (int q = 0; q < 4; ++q) {
                int row = lk * 4 + q;                 // C/D: row=(lane>>4)*4+reg, col=lane&15
                Z_lds[row * 128 + ZSWZ(row, w * 32 + lc)]      = z0[q];
                Z_lds[row * 128 + ZSWZ(row, w * 32 + 16 + lc)] = z1[q];
            }
        }
        __syncthreads();

        // ---- elementwise gates + state update; thread owns (row er, hcols ej, ej+16)
        {
            const float* zr = Z_lds + er * 128;
            unsigned short* hdst = (L == 0) ? (h1 + (size_t)t * (NB * NH))
                                            : (hb2 + (size_t)(t & 1) * (NB * NH));
            {
                float iv = zr[ZSWZ(er, ej)]       + bi_i0;
                float gv = zr[ZSWZ(er, 32 + ej)]  + bi_j0;
                float fv = zr[ZSWZ(er, 64 + ej)]  + bi_f0;   // includes FORGET_BIAS
                float ov = zr[ZSWZ(er, 96 + ej)]  + bi_o0;
                c0 = c0 * sigf(fv) + sigf(iv) * tanh_fast(gv);
                float hv = tanh_fast(c0) * sigf(ov);
                hdst[(size_t)brow_e * NH + jg0] = f2bf(hv);
                if (L) out[((size_t)brow_e * NT + t) * NH + jg0] = hv;
            }
            {
                float iv = zr[ZSWZ(er, 16 + ej)]  + bi_i1;
                float gv = zr[ZSWZ(er, 48 + ej)]  + bi_j1;
                float fv = zr[ZSWZ(er, 80 + ej)]  + bi_f1;
                float ov = zr[ZSWZ(er, 112 + ej)] + bi_o1;
                c1 = c1 * sigf(fv) + sigf(iv) * tanh_fast(gv);
                float hv = tanh_fast(c1) * sigf(ov);
                hdst[(size_t)brow_e * NH + jg1] = f2bf(hv);
                if (L) out[((size_t)brow_e * NT + t) * NH + jg1] = hv;
            }
        }
        __threadfence();          // drain h-writes to agent visibility (cross-XCD)
        __syncthreads();
        if (tid == 0)
            __hip_atomic_fetch_add(&mycnt[t], 1, __ATOMIC_RELEASE, __HIP_MEMORY_SCOPE_AGENT);
    }
}

extern "C" void kernel_launch(void* const* d_in, const int* in_sizes, int n_in,
                              void* d_out, int out_size, void* d_ws, size_t ws_size,
                              hipStream_t stream) {
    (void)in_sizes; (void)n_in; (void)out_size;
    const float* X  = (const float*)d_in[0];
    const float* W1 = (const float*)d_in[1];
    const float* b1 = (const float*)d_in[2];
    const float* W2 = (const float*)d_in[3];
    const float* b2 = (const float*)d_in[4];
    float* out = (float*)d_out;

    char* ws = (char*)d_ws;
    const size_t o_cnt = 0;                                    // 32 KB counters
    const size_t o_xt  = 65536;                                // Xt bf16: 64 MB
    const size_t o_h1  = o_xt + (size_t)NT * NB * NH * 2;      // h1 bf16: 64 MB
    const size_t o_hb2 = o_h1 + (size_t)NT * NB * NH * 2;      // h2 ping-pong: 128 KB
    const size_t o_wp  = o_hb2 + (size_t)2 * NB * NH * 2;      // packed W: 8 MB
    const size_t o_end = o_wp + (size_t)2 * 16 * 4 * 2 * 16 * 1024 * 2;
    if (ws_size < o_end) return;  // clean validation failure, not memory corruption

    int* cnt = (int*)(ws + o_cnt);
    unsigned short* Xt  = (unsigned short*)(ws + o_xt);
    unsigned short* h1  = (unsigned short*)(ws + o_h1);
    unsigned short* hb2 = (unsigned short*)(ws + o_hb2);
    unsigned short* Wp  = (unsigned short*)(ws + o_wp);

    hipMemsetAsync(ws + o_cnt, 0, (size_t)2 * 4 * NT * sizeof(int), stream);
    cvt_x_kernel<<<16384, 256, 0, stream>>>(X, Xt);
    pack_w_kernel<<<2048, 256, 0, stream>>>(W1, W2, Wp);
    lstm_kernel<<<128, 256, 0, stream>>>(Xt, h1, hb2, Wp, b1, b2, out, cnt);
}

// Round 5
// 6938.371 us; speedup vs baseline: 3.4568x; 3.4568x over previous
//
#include <hip/hip_runtime.h>
#include <hip/hip_bf16.h>
#include <stdint.h>

// 2-layer LSTM, B=64, T=1024, D=H=512.
// Persistent pipelined kernel: 128 WGs = 2 layers x 4 row-islands x 16 WGs.
// Each WG: 16 batch rows x 32 h-cols, 4 waves (wave = gate), W in 256 VGPRs.
// Island-local flag sync per timestep; layer 2 trails layer 1 by one step.
// bi&7 -> (layer,island): island's 16 WGs land on one XCD under %8 round-robin
// (perf heuristic only — correctness is placement-independent: all cross-WG
// data moves through IF-coherent sc1 loads/stores, never through L2).

typedef short short8 __attribute__((ext_vector_type(8)));
typedef float f32x4 __attribute__((ext_vector_type(4)));

#define NT 1024
#define NB 64
#define NH 512
#define WG_PER_ISL 16
// poll iter ~= 760cy (IF load + s_sleep) -> cap ~6ms; legit waits are <100us.
#define SPIN_CAP 20000u

// Z_lds column swizzle: flips col bit4 keyed by row parity ^ row bit2.
// Writes (lanes differ in row bits 2-3) and reads (lanes differ in row bits 0-1)
// both become 2-way bank aliasing (free per m136) instead of 4-way.
#define ZSWZ(row, col) ((col) ^ ((((row) ^ ((row) >> 2)) & 1) << 4))

static __device__ __forceinline__ unsigned short f2bf(float f) {
    union { float f; unsigned u; } v; v.f = f;
    unsigned r = (v.u + 0x7fffu + ((v.u >> 16) & 1u)) >> 16;  // RNE
    return (unsigned short)r;
}
static __device__ __forceinline__ float sigf(float x) {
    return 1.0f / (1.0f + __expf(-x));
}
static __device__ __forceinline__ float tanh_fast(float x) {
    return 1.0f - 2.0f / (1.0f + __expf(2.0f * x));
}

// X [64][1024][512] f32 -> Xt [1024][64][512] bf16
__global__ void cvt_x_kernel(const float* __restrict__ X, unsigned short* __restrict__ Xt) {
    unsigned id = blockIdx.x * 256 + threadIdx.x;   // 4,194,304 threads, 8 elems each
    unsigned d8 = id & 63u;
    unsigned t  = (id >> 6) & 1023u;
    unsigned b  = id >> 16;
    const f32x4* src = (const f32x4*)(X + (((size_t)b * NT + t) * NH) + d8 * 8);
    f32x4 v0 = src[0], v1 = src[1];
    short8 o;
    #pragma unroll
    for (int j = 0; j < 4; ++j) o[j] = (short)f2bf(v0[j]);
    #pragma unroll
    for (int j = 0; j < 4; ++j) o[4 + j] = (short)f2bf(v1[j]);
    *(short8*)(Xt + (((size_t)t * NB + b) * NH) + d8 * 8) = o;
}

// W[l] [1024][2048] f32 -> Wp [l][wgi][g][h][c16][k1024] bf16 (B-fragment order)
__global__ void pack_w_kernel(const float* __restrict__ W1, const float* __restrict__ W2,
                              unsigned short* __restrict__ Wp) {
    unsigned id = blockIdx.x * 256 + threadIdx.x;  // 524,288 threads, 8 k each
    unsigned k8  = id & 127u;
    unsigned c   = (id >> 7) & 15u;
    unsigned h   = (id >> 11) & 1u;
    unsigned g   = (id >> 12) & 3u;
    unsigned wgi = (id >> 14) & 15u;
    unsigned l   = id >> 18;
    const float* W = l ? W2 : W1;
    unsigned n = g * 512u + wgi * 32u + h * 16u + c;
    short8 o;
    #pragma unroll
    for (int j = 0; j < 8; ++j) o[j] = (short)f2bf(W[(size_t)(k8 * 8 + j) * 2048 + n]);
    *(short8*)(Wp + (size_t)id * 8) = o;
}

__global__ __launch_bounds__(256, 1)
void lstm_kernel(const unsigned short* __restrict__ Xt,   // [1024][64][512] bf16
                 unsigned short* __restrict__ h1,         // [1024][64][512] bf16
                 unsigned short* __restrict__ hb2,        // [2][64][512] bf16 ping-pong
                 const unsigned short* __restrict__ Wp,   // packed weights bf16
                 const float* __restrict__ b1,
                 const float* __restrict__ b2,
                 float* __restrict__ out,                 // [64][1024][512] f32
                 int* __restrict__ cnt)                   // [2][4][1024]
{
    const int bi  = blockIdx.x;
    const int L   = (bi >> 2) & 1;
    const int isl = bi & 3;
    const int wgi = bi >> 3;          // 0..15
    const int tid = threadIdx.x;
    const int wv  = tid >> 6;         // wave index == gate index (i,j,f,o)
    const int ln  = tid & 63;

    __shared__ alignas(16) unsigned short A_lds[16 * 1024]; // [16 rows][1024 k], XOR-swizzled
    __shared__ float Z_lds[16 * 128];                       // [16 rows][4 gates * 32 hcols]

    const int lc = ln & 15;
    const int lk = ln >> 4;

    // ---- persistent weight fragments: wave wv, cols n = wv*512 + wgi*32 + {0..31}
    short8 wf0[32], wf1[32];
    {
        const unsigned short* wb = Wp + ((((size_t)L * 16 + wgi) * 4 + wv) * 2) * (16 * 1024);
        #pragma unroll
        for (int ks = 0; ks < 32; ++ks) {
            wf0[ks] = *(const short8*)(wb + (size_t)lc * 1024 + ks * 32 + lk * 8);
            wf1[ks] = *(const short8*)(wb + (size_t)(16 + lc) * 1024 + ks * 32 + lk * 8);
        }
    }

    float c0 = 0.0f, c1 = 0.0f;       // cell state, owned per-thread
    const int er = tid >> 4;          // row 0..15
    const int ej = tid & 15;          // hcol_local (and +16)
    const int brow_e = isl * 16 + er;

    // ---- hoist loop-invariant biases into registers (FORGET_BIAS pre-folded)
    const float* bias = L ? b2 : b1;
    const int jg0 = wgi * 32 + ej, jg1 = jg0 + 16;
    const float bi_i0 = bias[jg0],          bi_i1 = bias[jg1];
    const float bi_j0 = bias[512 + jg0],    bi_j1 = bias[512 + jg1];
    const float bi_f0 = bias[1024 + jg0] + 1.0f, bi_f1 = bias[1024 + jg1] + 1.0f;
    const float bi_o0 = bias[1536 + jg0],   bi_o1 = bias[1536 + jg1];

    int* mycnt  = cnt + (L * 4 + isl) * NT;
    int* depcnt = cnt + isl * NT;     // layer-1 counters (dep for L==1)

    for (int t = 0; t < NT; ++t) {
        // ---- concurrent region: poll flags (wave1 lanes 0,1) || L0 x-prestage (waves 0,2)
        if (wv == 1 && ln < 2) {
            // lane0: own island's previous step; lane1: layer-1 dependency (L==1 only)
            const bool act = (ln == 0) ? (t > 0) : (L == 1);
            if (act) {
                int* a = (ln == 0) ? &mycnt[t - 1] : &depcnt[t];
                unsigned sp = 0;
                while (__hip_atomic_load(a, __ATOMIC_RELAXED, __HIP_MEMORY_SCOPE_AGENT) < WG_PER_ISL
                       && ++sp < SPIN_CAP) __builtin_amdgcn_s_sleep(1);
            }
        }
        if (L == 0 && (wv & 1) == 0) {
            // Xt[t] is dependency-free: stage x-half (cached loads) while wave1 polls
            const unsigned short* xsrc = Xt + (size_t)t * (NB * NH);
            #pragma unroll
            for (int p = 0; p < 8; ++p) {
                int r = 2 * p + (wv >> 1);
                int br = isl * 16 + r;
                short8 v = *(const short8*)(xsrc + (size_t)br * NH + ln * 8);
                *(short8*)((char*)A_lds + r * 2048 + ((ln ^ (r & 7)) << 4)) = v;
            }
        }
        __syncthreads();  // #1: flags seen -> dependent staging may start

        // ---- stage cross-WG data via IF-coherent (sc1) loads; never touches L2
        if (L == 0) {
            if (wv & 1) {  // waves 1,3: h-half, s = 64+ln
                unsigned short* hsrc = h1 + (size_t)(t > 0 ? t - 1 : 0) * (NB * NH);
                #pragma unroll
                for (int p = 0; p < 8; ++p) {
                    int r = 2 * p + (wv >> 1);
                    int br = isl * 16 + r;
                    char* dst = (char*)A_lds + r * 2048 + (((64 + ln) ^ (r & 7)) << 4);
                    unsigned long long q0 = 0ull, q1 = 0ull;
                    if (t > 0) {
                        unsigned long long* q = (unsigned long long*)(hsrc + (size_t)br * NH + ln * 8);
                        q0 = __hip_atomic_load(q,     __ATOMIC_RELAXED, __HIP_MEMORY_SCOPE_AGENT);
                        q1 = __hip_atomic_load(q + 1, __ATOMIC_RELAXED, __HIP_MEMORY_SCOPE_AGENT);
                    }
                    *(unsigned long long*)dst = q0;
                    *(unsigned long long*)(dst + 8) = q1;
                }
            }
        } else {
            // L1: both halves are cross-WG data (x = h1[t], h = hb2 ping-pong)
            const bool xhalf = ((wv & 1) == 0);
            unsigned short* src = xhalf ? (h1 + (size_t)t * (NB * NH))
                                        : (hb2 + (size_t)((t + 1) & 1) * (NB * NH));
            const int s = xhalf ? ln : (64 + ln);
            const bool rd = xhalf || (t > 0);
            #pragma unroll
            for (int p = 0; p < 8; ++p) {
                int r = 2 * p + (wv >> 1);
                int br = isl * 16 + r;
                char* dst = (char*)A_lds + r * 2048 + ((s ^ (r & 7)) << 4);
                unsigned long long q0 = 0ull, q1 = 0ull;
                if (rd) {
                    unsigned long long* q = (unsigned long long*)(src + (size_t)br * NH + ln * 8);
                    q0 = __hip_atomic_load(q,     __ATOMIC_RELAXED, __HIP_MEMORY_SCOPE_AGENT);
                    q1 = __hip_atomic_load(q + 1, __ATOMIC_RELAXED, __HIP_MEMORY_SCOPE_AGENT);
                }
                *(unsigned long long*)dst = q0;
                *(unsigned long long*)(dst + 8) = q1;
            }
        }
        __syncthreads();  // #2: A-tile ready

        // ---- Z = A @ W (K=1024), per wave: 2 col-tiles x 32 k-steps, 2 acc chains each
        {
            f32x4 a00 = {0,0,0,0}, a01 = {0,0,0,0}, a10 = {0,0,0,0}, a11 = {0,0,0,0};
            const char* ab = (const char*)A_lds + lc * 2048;
            const int sw = lc & 7;
            #pragma unroll
            for (int ks = 0; ks < 32; ++ks) {
                short8 a = *(const short8*)(ab + (((ks * 4 + lk) ^ sw) << 4));
                if (ks & 1) {
                    a01 = __builtin_amdgcn_mfma_f32_16x16x32_bf16(a, wf0[ks], a01, 0, 0, 0);
                    a11 = __builtin_amdgcn_mfma_f32_16x16x32_bf16(a, wf1[ks], a11, 0, 0, 0);
                } else {
                    a00 = __builtin_amdgcn_mfma_f32_16x16x32_bf16(a, wf0[ks], a00, 0, 0, 0);
                    a10 = __builtin_amdgcn_mfma_f32_16x16x32_bf16(a, wf1[ks], a10, 0, 0, 0);
                }
            }
            f32x4 z0 = a00 + a01, z1 = a10 + a11;
            #pragma unroll
            for (int q = 0; q < 4; ++q) {
                int row = lk * 4 + q;                 // C/D: row=(lane>>4)*4+reg, col=lane&15
                Z_lds[row * 128 + ZSWZ(row, wv * 32 + lc)]      = z0[q];
                Z_lds[row * 128 + ZSWZ(row, wv * 32 + 16 + lc)] = z1[q];
            }
        }
        __syncthreads();  // #3: Z ready

        // ---- elementwise gates + state update; thread owns (row er, hcols ej, ej+16)
        {
            const float* zr = Z_lds + er * 128;
            unsigned short* hdst = (L == 0) ? (h1 + (size_t)t * (NB * NH))
                                            : (hb2 + (size_t)(t & 1) * (NB * NH));
            {
                float iv = zr[ZSWZ(er, ej)]       + bi_i0;
                float gv = zr[ZSWZ(er, 32 + ej)]  + bi_j0;
                float fv = zr[ZSWZ(er, 64 + ej)]  + bi_f0;   // includes FORGET_BIAS
                float ov = zr[ZSWZ(er, 96 + ej)]  + bi_o0;
                c0 = c0 * sigf(fv) + sigf(iv) * tanh_fast(gv);
                float hv = tanh_fast(c0) * sigf(ov);
                __hip_atomic_store(hdst + (size_t)brow_e * NH + jg0, f2bf(hv),
                                   __ATOMIC_RELAXED, __HIP_MEMORY_SCOPE_AGENT);
                if (L) out[((size_t)brow_e * NT + t) * NH + jg0] = hv;  // cached; off critical path
            }
            {
                float iv = zr[ZSWZ(er, 16 + ej)]  + bi_i1;
                float gv = zr[ZSWZ(er, 48 + ej)]  + bi_j1;
                float fv = zr[ZSWZ(er, 80 + ej)]  + bi_f1;
                float ov = zr[ZSWZ(er, 112 + ej)] + bi_o1;
                c1 = c1 * sigf(fv) + sigf(iv) * tanh_fast(gv);
                float hv = tanh_fast(c1) * sigf(ov);
                __hip_atomic_store(hdst + (size_t)brow_e * NH + jg1, f2bf(hv),
                                   __ATOMIC_RELAXED, __HIP_MEMORY_SCOPE_AGENT);
                if (L) out[((size_t)brow_e * NT + t) * NH + jg1] = hv;
            }
        }
        // #4: drains each thread's vmcnt -> all sc1 h-stores visible at IF before publish.
        __syncthreads();
        if (tid == 0)
            __hip_atomic_fetch_add(&mycnt[t], 1, __ATOMIC_RELAXED, __HIP_MEMORY_SCOPE_AGENT);
    }
}

extern "C" void kernel_launch(void* const* d_in, const int* in_sizes, int n_in,
                              void* d_out, int out_size, void* d_ws, size_t ws_size,
                              hipStream_t stream) {
    (void)in_sizes; (void)n_in; (void)out_size;
    const float* X  = (const float*)d_in[0];
    const float* W1 = (const float*)d_in[1];
    const float* b1 = (const float*)d_in[2];
    const float* W2 = (const float*)d_in[3];
    const float* b2 = (const float*)d_in[4];
    float* out = (float*)d_out;

    char* ws = (char*)d_ws;
    const size_t o_cnt = 0;                                    // 32 KB counters
    const size_t o_xt  = 65536;                                // Xt bf16: 64 MB
    const size_t o_h1  = o_xt + (size_t)NT * NB * NH * 2;      // h1 bf16: 64 MB
    const size_t o_hb2 = o_h1 + (size_t)NT * NB * NH * 2;      // h2 ping-pong: 128 KB
    const size_t o_wp  = o_hb2 + (size_t)2 * NB * NH * 2;      // packed W: 8 MB
    const size_t o_end = o_wp + (size_t)2 * 16 * 4 * 2 * 16 * 1024 * 2;
    if (ws_size < o_end) return;  // clean validation failure, not memory corruption

    int* cnt = (int*)(ws + o_cnt);
    unsigned short* Xt  = (unsigned short*)(ws + o_xt);
    unsigned short* h1  = (unsigned short*)(ws + o_h1);
    unsigned short* hb2 = (unsigned short*)(ws + o_hb2);
    unsigned short* Wp  = (unsigned short*)(ws + o_wp);

    hipMemsetAsync(ws + o_cnt, 0, (size_t)2 * 4 * NT * sizeof(int), stream);
    cvt_x_kernel<<<16384, 256, 0, stream>>>(X, Xt);
    pack_w_kernel<<<2048, 256, 0, stream>>>(W1, W2, Wp);
    lstm_kernel<<<128, 256, 0, stream>>>(Xt, h1, hb2, Wp, b1, b2, out, cnt);
}

// Round 6
// 4246.813 us; speedup vs baseline: 5.6477x; 1.6338x over previous
//
#include <hip/hip_runtime.h>
#include <hip/hip_bf16.h>
#include <stdint.h>

// 2-layer LSTM, B=64, T=1024, D=H=512.
// Persistent pipelined kernel: 128 WGs = 2 layers x 4 row-islands x 16 WGs.
// Per step, only the dependency-half GEMM (K=512) is on the critical path:
//  L0 pre-computes x@Wx for t+1 in the publish shadow (acc carried in VGPRs);
//  L1 pre-computes h2[t-1]@Wh while waiting for h1[t].
// Sync = per-WG flag words at IF (sc1 stores, no RMW) + 16-lane parallel poll.
// All cross-WG data via agent-scope (sc1) loads/stores -> no L2 flush/inv.

typedef short short8 __attribute__((ext_vector_type(8)));
typedef float f32x4 __attribute__((ext_vector_type(4)));

#define NT 1024
#define NB 64
#define NH 512
// bare-spin iter ~700cy (IF load) -> cap ~6ms; legit waits are <100us.
#define SPIN_CAP 20000u

// Z_lds column swizzle: flips col bit4 keyed by row parity ^ row bit2.
#define ZSWZ(row, col) ((col) ^ ((((row) ^ ((row) >> 2)) & 1) << 4))

static __device__ __forceinline__ unsigned short f2bf(float f) {
    union { float f; unsigned u; } v; v.f = f;
    unsigned r = (v.u + 0x7fffu + ((v.u >> 16) & 1u)) >> 16;  // RNE
    return (unsigned short)r;
}
static __device__ __forceinline__ float sigf(float x) {
    return 1.0f / (1.0f + __expf(-x));
}
static __device__ __forceinline__ float tanh_fast(float x) {
    return 1.0f - 2.0f / (1.0f + __expf(2.0f * x));
}

// X [64][1024][512] f32 -> Xt [1024][64][512] bf16
__global__ void cvt_x_kernel(const float* __restrict__ X, unsigned short* __restrict__ Xt) {
    unsigned id = blockIdx.x * 256 + threadIdx.x;
    unsigned d8 = id & 63u;
    unsigned t  = (id >> 6) & 1023u;
    unsigned b  = id >> 16;
    const f32x4* src = (const f32x4*)(X + (((size_t)b * NT + t) * NH) + d8 * 8);
    f32x4 v0 = src[0], v1 = src[1];
    short8 o;
    #pragma unroll
    for (int j = 0; j < 4; ++j) o[j] = (short)f2bf(v0[j]);
    #pragma unroll
    for (int j = 0; j < 4; ++j) o[4 + j] = (short)f2bf(v1[j]);
    *(short8*)(Xt + (((size_t)t * NB + b) * NH) + d8 * 8) = o;
}

// W[l] [1024][2048] f32 -> Wp [l][wgi][g][h][c16][k1024] bf16 (B-fragment order)
__global__ void pack_w_kernel(const float* __restrict__ W1, const float* __restrict__ W2,
                              unsigned short* __restrict__ Wp) {
    unsigned id = blockIdx.x * 256 + threadIdx.x;
    unsigned k8  = id & 127u;
    unsigned c   = (id >> 7) & 15u;
    unsigned h   = (id >> 11) & 1u;
    unsigned g   = (id >> 12) & 3u;
    unsigned wgi = (id >> 14) & 15u;
    unsigned l   = id >> 18;
    const float* W = l ? W2 : W1;
    unsigned n = g * 512u + wgi * 32u + h * 16u + c;
    short8 o;
    #pragma unroll
    for (int j = 0; j < 8; ++j) o[j] = (short)f2bf(W[(size_t)(k8 * 8 + j) * 2048 + n]);
    *(short8*)(Wp + (size_t)id * 8) = o;
}

// One K=512 half-GEMM: 16 k-steps over A_lds slot range [base, base+64).
static __device__ __forceinline__ void gemm_half(const char* ab, int sw, int lk, int base,
        const short8* w0, const short8* w1,
        f32x4& a00, f32x4& a01, f32x4& a10, f32x4& a11) {
    #pragma unroll
    for (int ks = 0; ks < 16; ++ks) {
        short8 a = *(const short8*)(ab + ((base + ((ks * 4 + lk) ^ sw)) << 4));
        if (ks & 1) {
            a01 = __builtin_amdgcn_mfma_f32_16x16x32_bf16(a, w0[ks], a01, 0, 0, 0);
            a11 = __builtin_amdgcn_mfma_f32_16x16x32_bf16(a, w1[ks], a11, 0, 0, 0);
        } else {
            a00 = __builtin_amdgcn_mfma_f32_16x16x32_bf16(a, w0[ks], a00, 0, 0, 0);
            a10 = __builtin_amdgcn_mfma_f32_16x16x32_bf16(a, w1[ks], a10, 0, 0, 0);
        }
    }
}

// Stage one 16rows x 512cols half via IF-coherent loads. Batched: issue all 8
// loads into regs first (one latency), then 4 ds_write_b128. Wave wv owns rows
// {wv, wv+4, wv+8, wv+12}; lane ln owns 16B chunk ln.
static __device__ __forceinline__ void stage_half_atomic(unsigned short* A,
        const unsigned short* src, int isl, int wv, int ln, int half, bool zero) {
    unsigned long long q[4][2];
    #pragma unroll
    for (int p = 0; p < 4; ++p) {
        q[p][0] = 0ull; q[p][1] = 0ull;
        if (!zero) {
            int br = isl * 16 + wv + 4 * p;
            const unsigned long long* s8 =
                (const unsigned long long*)(src + (size_t)br * NH + ln * 8);
            q[p][0] = __hip_atomic_load(s8,     __ATOMIC_RELAXED, __HIP_MEMORY_SCOPE_AGENT);
            q[p][1] = __hip_atomic_load(s8 + 1, __ATOMIC_RELAXED, __HIP_MEMORY_SCOPE_AGENT);
        }
    }
    const int s = half * 64 + ln;
    #pragma unroll
    for (int p = 0; p < 4; ++p) {
        int r = wv + 4 * p;
        char* dst = (char*)A + r * 2048 + ((s ^ (r & 7)) << 4);
        *(unsigned long long*)dst = q[p][0];
        *(unsigned long long*)(dst + 8) = q[p][1];
    }
}

// Plain-cached variant for Xt (static data, L2-friendly). x-half (slots 0..63).
static __device__ __forceinline__ void stage_half_plain(unsigned short* A,
        const unsigned short* src, int isl, int wv, int ln) {
    short8 v[4];
    #pragma unroll
    for (int p = 0; p < 4; ++p) {
        int br = isl * 16 + wv + 4 * p;
        v[p] = *(const short8*)(src + (size_t)br * NH + ln * 8);
    }
    #pragma unroll
    for (int p = 0; p < 4; ++p) {
        int r = wv + 4 * p;
        char* dst = (char*)A + r * 2048 + ((ln ^ (r & 7)) << 4);
        *(short8*)dst = v[p];
    }
}

// 16-lane parallel poll on per-WG flag words (no RMW anywhere).
static __device__ __forceinline__ void poll16(const int* f, int tid) {
    if (tid < 16) {
        unsigned sp = 0;
        while (__hip_atomic_load(f + tid, __ATOMIC_RELAXED, __HIP_MEMORY_SCOPE_AGENT) == 0
               && ++sp < SPIN_CAP) {}
    }
}

__global__ __launch_bounds__(256, 1)
void lstm_kernel(const unsigned short* __restrict__ Xt,   // [1024][64][512] bf16
                 unsigned short* __restrict__ h1,         // [1024][64][512] bf16
                 unsigned short* __restrict__ hb2,        // [2][64][512] bf16 ping-pong
                 const unsigned short* __restrict__ Wp,   // packed weights bf16
                 const float* __restrict__ b1,
                 const float* __restrict__ b2,
                 float* __restrict__ out,                 // [64][1024][512] f32
                 int* __restrict__ flags)                 // [2][4][1024][16]
{
    const int bi  = blockIdx.x;
    const int L   = (bi >> 2) & 1;
    const int isl = bi & 3;
    const int wgi = bi >> 3;          // 0..15
    const int tid = threadIdx.x;
    const int wv  = tid >> 6;         // wave index == gate index (i,j,f,o)
    const int ln  = tid & 63;

    __shared__ alignas(16) unsigned short A_lds[16 * 1024]; // [16 rows][1024 k], XOR-swizzled
    __shared__ float Z_lds[16 * 128];                       // [16 rows][4 gates * 32 hcols]

    const int lc = ln & 15;
    const int lk = ln >> 4;
    const char* ab = (const char*)A_lds + lc * 2048;
    const int sw = lc & 7;

    // ---- persistent weight fragments: wave wv, cols n = wv*512 + wgi*32 + {0..31}
    // wf[0..15] = K rows 0..511 (x-half), wf[16..31] = K rows 512..1023 (h-half)
    short8 wf0[32], wf1[32];
    {
        const unsigned short* wb = Wp + ((((size_t)L * 16 + wgi) * 4 + wv) * 2) * (16 * 1024);
        #pragma unroll
        for (int ks = 0; ks < 32; ++ks) {
            wf0[ks] = *(const short8*)(wb + (size_t)lc * 1024 + ks * 32 + lk * 8);
            wf1[ks] = *(const short8*)(wb + (size_t)(16 + lc) * 1024 + ks * 32 + lk * 8);
        }
    }

    float c0 = 0.0f, c1 = 0.0f;       // cell state, owned per-thread
    const int er = tid >> 4;          // row 0..15
    const int ej = tid & 15;          // hcol_local (and +16)
    const int brow_e = isl * 16 + er;

    const float* bias = L ? b2 : b1;
    const int jg0 = wgi * 32 + ej, jg1 = jg0 + 16;
    const float bi_i0 = bias[jg0],          bi_i1 = bias[jg1];
    const float bi_j0 = bias[512 + jg0],    bi_j1 = bias[512 + jg1];
    const float bi_f0 = bias[1024 + jg0] + 1.0f, bi_f1 = bias[1024 + jg1] + 1.0f;
    const float bi_o0 = bias[1536 + jg0],   bi_o1 = bias[1536 + jg1];

    int* flg_own = flags + ((L * 4 + isl) * NT) * 16;
    int* flg_dep = flags + ((0 * 4 + isl) * NT) * 16;   // layer-1 flags (dep for L==1)

    f32x4 a00 = {0,0,0,0}, a01 = {0,0,0,0}, a10 = {0,0,0,0}, a11 = {0,0,0,0};

    // finish-z + gates + h/out stores (call sites are block-uniform)
    int t_cur = 0;
    auto finish = [&]() {
        f32x4 z0 = a00 + a01, z1 = a10 + a11;
        #pragma unroll
        for (int q = 0; q < 4; ++q) {
            int row = lk * 4 + q;                 // C/D: row=(lane>>4)*4+reg, col=lane&15
            Z_lds[row * 128 + ZSWZ(row, wv * 32 + lc)]      = z0[q];
            Z_lds[row * 128 + ZSWZ(row, wv * 32 + 16 + lc)] = z1[q];
        }
        __syncthreads();  // Z ready
        const float* zr = Z_lds + er * 128;
        unsigned short* hdst = (L == 0) ? (h1 + (size_t)t_cur * (NB * NH))
                                        : (hb2 + (size_t)(t_cur & 1) * (NB * NH));
        {
            float iv = zr[ZSWZ(er, ej)]       + bi_i0;
            float gv = zr[ZSWZ(er, 32 + ej)]  + bi_j0;
            float fv = zr[ZSWZ(er, 64 + ej)]  + bi_f0;   // includes FORGET_BIAS
            float ov = zr[ZSWZ(er, 96 + ej)]  + bi_o0;
            c0 = c0 * sigf(fv) + sigf(iv) * tanh_fast(gv);
            float hv = tanh_fast(c0) * sigf(ov);
            __hip_atomic_store(hdst + (size_t)brow_e * NH + jg0, f2bf(hv),
                               __ATOMIC_RELAXED, __HIP_MEMORY_SCOPE_AGENT);
            if (L) out[((size_t)brow_e * NT + t_cur) * NH + jg0] = hv;
        }
        {
            float iv = zr[ZSWZ(er, 16 + ej)]  + bi_i1;
            float gv = zr[ZSWZ(er, 48 + ej)]  + bi_j1;
            float fv = zr[ZSWZ(er, 80 + ej)]  + bi_f1;
            float ov = zr[ZSWZ(er, 112 + ej)] + bi_o1;
            c1 = c1 * sigf(fv) + sigf(iv) * tanh_fast(gv);
            float hv = tanh_fast(c1) * sigf(ov);
            __hip_atomic_store(hdst + (size_t)brow_e * NH + jg1, f2bf(hv),
                               __ATOMIC_RELAXED, __HIP_MEMORY_SCOPE_AGENT);
            if (L) out[((size_t)brow_e * NT + t_cur) * NH + jg1] = hv;
        }
        // syncthreads at the call site drains vmcnt per thread (sc1 stores at IF)
        // before tid0 publishes -> flag ordered after data.
    };

    if (L == 0) {
        // prologue: zx for t=0
        stage_half_plain(A_lds, Xt, isl, wv, ln);
        __syncthreads();
        gemm_half(ab, sw, lk, 0, wf0, wf1, a00, a01, a10, a11);
    }

    for (int t = 0; t < NT; ++t) {
        t_cur = t;
        if (L == 0) {
            // critical hop: poll own(t-1) -> stage h1[t-1] -> h-half GEMM -> gates -> publish
            if (t > 0) poll16(flg_own + (t - 1) * 16, tid);
            __syncthreads();
            stage_half_atomic(A_lds, h1 + (size_t)(t > 0 ? t - 1 : 0) * (NB * NH),
                              isl, wv, ln, 1, t == 0);
            __syncthreads();
            gemm_half(ab, sw, lk, 64, wf0 + 16, wf1 + 16, a00, a01, a10, a11);
            finish();
            __syncthreads();  // drain sc1 stores, then publish
            if (tid == 0)
                __hip_atomic_store(flg_own + t * 16 + wgi, 1,
                                   __ATOMIC_RELAXED, __HIP_MEMORY_SCOPE_AGENT);
            // publish shadow: pre-GEMM x-half for t+1 (dependency-free)
            if (t + 1 < NT) {
                stage_half_plain(A_lds, Xt + (size_t)(t + 1) * (NB * NH), isl, wv, ln);
                __syncthreads();
                a00 = {0,0,0,0}; a01 = {0,0,0,0}; a10 = {0,0,0,0}; a11 = {0,0,0,0};
                gemm_half(ab, sw, lk, 0, wf0, wf1, a00, a01, a10, a11);
            }
        } else {
            // wait shadow: own h2[t-1] half first (own island, usually ready)
            if (t > 0) poll16(flg_own + (t - 1) * 16, tid);
            __syncthreads();
            stage_half_atomic(A_lds, hb2 + (size_t)((t + 1) & 1) * (NB * NH),
                              isl, wv, ln, 1, t == 0);
            __syncthreads();
            a00 = {0,0,0,0}; a01 = {0,0,0,0}; a10 = {0,0,0,0}; a11 = {0,0,0,0};
            gemm_half(ab, sw, lk, 64, wf0 + 16, wf1 + 16, a00, a01, a10, a11);
            // critical hop: poll dep(t) -> stage h1[t] -> x-half GEMM -> gates -> publish
            poll16(flg_dep + t * 16, tid);
            __syncthreads();
            stage_half_atomic(A_lds, h1 + (size_t)t * (NB * NH), isl, wv, ln, 0, false);
            __syncthreads();
            gemm_half(ab, sw, lk, 0, wf0, wf1, a00, a01, a10, a11);
            finish();
            __syncthreads();  // drain sc1 stores, then publish
            if (tid == 0)
                __hip_atomic_store(flg_own + t * 16 + wgi, 1,
                                   __ATOMIC_RELAXED, __HIP_MEMORY_SCOPE_AGENT);
        }
    }
}

extern "C" void kernel_launch(void* const* d_in, const int* in_sizes, int n_in,
                              void* d_out, int out_size, void* d_ws, size_t ws_size,
                              hipStream_t stream) {
    (void)in_sizes; (void)n_in; (void)out_size;
    const float* X  = (const float*)d_in[0];
    const float* W1 = (const float*)d_in[1];
    const float* b1 = (const float*)d_in[2];
    const float* W2 = (const float*)d_in[3];
    const float* b2 = (const float*)d_in[4];
    float* out = (float*)d_out;

    char* ws = (char*)d_ws;
    const size_t o_flg = 0;                                    // flags: 512 KB
    const size_t sz_flg = (size_t)2 * 4 * NT * 16 * sizeof(int);
    const size_t o_xt  = o_flg + sz_flg;                       // Xt bf16: 64 MB
    const size_t o_h1  = o_xt + (size_t)NT * NB * NH * 2;      // h1 bf16: 64 MB
    const size_t o_hb2 = o_h1 + (size_t)NT * NB * NH * 2;      // h2 ping-pong: 128 KB
    const size_t o_wp  = o_hb2 + (size_t)2 * NB * NH * 2;      // packed W: 8 MB
    const size_t o_end = o_wp + (size_t)2 * 16 * 4 * 2 * 16 * 1024 * 2;
    if (ws_size < o_end) return;  // clean validation failure, not memory corruption

    int* flags = (int*)(ws + o_flg);
    unsigned short* Xt  = (unsigned short*)(ws + o_xt);
    unsigned short* h1  = (unsigned short*)(ws + o_h1);
    unsigned short* hb2 = (unsigned short*)(ws + o_hb2);
    unsigned short* Wp  = (unsigned short*)(ws + o_wp);

    hipMemsetAsync(ws + o_flg, 0, sz_flg, stream);
    cvt_x_kernel<<<16384, 256, 0, stream>>>(X, Xt);
    pack_w_kernel<<<2048, 256, 0, stream>>>(W1, W2, Wp);
    lstm_kernel<<<128, 256, 0, stream>>>(Xt, h1, hb2, Wp, b1, b2, out, flags);
}